// Round 9
// baseline (89.818 us; speedup 1.0000x reference)
//
#include <hip/hip_runtime.h>
#include <hip/hip_bf16.h>
#include <math.h>

// Problem constants: T=4096, B=64, D=64, SCALE = 1/8.
#define T_DIM 4096
#define B_DIM 64
#define NROWS (T_DIM * B_DIM)   // 262144 rows (r = t*64+b), 64 floats each
#define NTILES (NROWS / 16)     // 16384 16-row MFMA tiles

// Workspace layout (float offsets)
#define WS_MFRAG 0        // 4096 u16 (2048 f): M fragment-linear bf16
#define WS_VFRAG 2048     // 4096 u16: Wv fragment-linear bf16
#define WS_UAF   4096     // 1024 u16 (512 f): u as A-fragment (row 0 = u)
#define WS_U     4608     // 64 f32
#define WS_W     4672     // 64 f32
#define WS_C     4736     // 1 f32
#define WS_MX    4752     // 64 f32
#define WS_INV   4816     // 64 f32
#define WS_PM    4880     // 64x64 f32 partial max
#define WS_PS    8976     // 64x64 f32 partial sum
#define WS_DBG   13072    // 16384 f32 probe scratch
#define WS_SCORE 32768    // [NROWS] scores, natural r order

typedef __attribute__((ext_vector_type(4))) float f32x4;
typedef __attribute__((ext_vector_type(8))) short bf16x8;

static __device__ inline short f2bf(float x) {
  __hip_bfloat16 h = __float2bfloat16(x);
  return *reinterpret_cast<short*>(&h);
}

static __device__ inline bf16x8 cvt8(const float4 a, const float4 b) {
  bf16x8 r;
  r[0] = f2bf(a.x); r[1] = f2bf(a.y); r[2] = f2bf(a.z); r[3] = f2bf(a.w);
  r[4] = f2bf(b.x); r[5] = f2bf(b.y); r[6] = f2bf(b.z); r[7] = f2bf(b.w);
  return r;
}

static __device__ inline float dot4(const float4 a, const float4 b, float acc) {
  acc = fmaf(a.x, b.x, acc); acc = fmaf(a.y, b.y, acc);
  acc = fmaf(a.z, b.z, acc); acc = fmaf(a.w, b.w, acc);
  return acc;
}

// Fragment-linear index (u16 units) for weight element W[d][k]:
// A/B-frag lane l holds row l&15, k-chunk l>>4 (8 contiguous k).
static __device__ __host__ inline int frag_idx(int d, int k) {
  return ((d >> 4) * 2 + (k >> 5)) * 512 +
         ((((k >> 3) & 3) * 16 + (d & 15)) * 8) + (k & 7);
}

// Issue one 16B/lane global->LDS staging op (no VGPR destination: the
// compiler cannot serialize these; all stay in flight until one vmcnt wait).
static __device__ inline void gll16(const float* src, float* ldsbase) {
  __builtin_amdgcn_global_load_lds(
      (const __attribute__((address_space(1))) unsigned int*)src,
      (__attribute__((address_space(3))) unsigned int*)ldsbase, 16, 0, 0);
}

// ---------------------------------------------------------------------------
// K1: bilinear constants; M and Wv bf16 fragment-linear; u also as A-frag.
__global__ __launch_bounds__(64) void k1_precompute(
    const float* __restrict__ Wq, const float* __restrict__ bq,
    const float* __restrict__ Wk, const float* __restrict__ bk,
    const float* __restrict__ Wv, float* __restrict__ ws) {
  const int tid = threadIdx.x;
  const int blk = blockIdx.x;
  unsigned short* __restrict__ mfrag = (unsigned short*)(ws + WS_MFRAG);
  unsigned short* __restrict__ vfrag = (unsigned short*)(ws + WS_VFRAG);
  unsigned short* __restrict__ uaf   = (unsigned short*)(ws + WS_UAF);
  if (blk < 64) {
    const int d = blk;
    float acc = 0.f;
#pragma unroll
    for (int o = 0; o < 64; ++o)
      acc = fmaf(Wq[o * 64 + d], Wk[o * 64 + tid], acc);
    const int idx = frag_idx(d, tid);
    mfrag[idx] = (unsigned short)f2bf(acc);
    vfrag[idx] = (unsigned short)f2bf(Wv[d * 64 + tid]);
  } else {
    __shared__ float ush[64];
    float uacc = 0.f, wacc = 0.f, cacc = 0.f;
#pragma unroll
    for (int o = 0; o < 64; ++o) {
      uacc = fmaf(bq[o], Wk[o * 64 + tid], uacc);
      wacc = fmaf(Wq[o * 64 + tid], bk[o], wacc);
      cacc = fmaf(bq[o], bk[o], cacc);
    }
    ush[tid] = uacc;
    ws[WS_U + tid] = uacc;
    ws[WS_W + tid] = wacc;
    if (tid == 0) ws[WS_C] = cacc;
    __syncthreads();
    // u A-fragment: lane tid holds A[row tid&15][k=(tid>>4)*8+e]; row0 = u.
#pragma unroll
    for (int h = 0; h < 2; ++h)
#pragma unroll
      for (int e = 0; e < 8; ++e)
        uaf[h * 512 + tid * 8 + e] =
            ((tid & 15) == 0)
                ? (unsigned short)f2bf(ush[h * 32 + (tid >> 4) * 8 + e])
                : (unsigned short)0;
  }
}

// ---------------------------------------------------------------------------
// K2: score[r] = 0.125*(e^T M f + w.e + u.f + c).
// One 16-row tile per wave. F staged TRANSPOSED via global_load_lds into a
// wave-private LDS slice (linear dest + permuted per-lane source); fragment
// ds_reads are 16B-consecutive per 16-lane group -> conflict-free. E, weights
// ride the same single vmcnt(0) drain. u.f via a 2-MFMA u-row.
template <int PROBE>
__global__ __launch_bounds__(256, 2) void k2_score_mfma(
    const float* __restrict__ eeg, const float* __restrict__ fnirs,
    const unsigned short* __restrict__ mfrag,
    const unsigned short* __restrict__ uafr,
    const float* __restrict__ wvec, const float* __restrict__ cvec,
    float* __restrict__ score, float* __restrict__ dbg) {
  __shared__ float fstage[4][1024];
  const int tid = threadIdx.x;
  const int lane = tid & 63;
  const int wv = tid >> 6;
  const int tile = blockIdx.x * 4 + wv;
  const int c = lane & 15;
  const int g = lane >> 4;
  const int rbase = tile * 16;
  float* L = fstage[wv];

  // --- staging: LDS unit (j2*16 + c) := F[rbase+c][16B-chunk j2] ---
#pragma unroll
  for (int q = 0; q < 4; ++q) {
    const float* src =
        fnirs + (size_t)(rbase + (lane & 15)) * 64 + (q * 4 + (lane >> 4)) * 4;
    gll16(src, &L[q * 256]);
  }
  // --- direct loads, all issued before the drain ---
  float4 Ed[4];
#pragma unroll
  for (int dt = 0; dt < 4; ++dt)
    Ed[dt] = *reinterpret_cast<const float4*>(
        eeg + (size_t)(rbase + c) * 64 + dt * 16 + g * 4);
  bf16x8 bm[4][2];
#pragma unroll
  for (int dt = 0; dt < 4; ++dt)
#pragma unroll
    for (int kf = 0; kf < 2; ++kf)
      bm[dt][kf] = *reinterpret_cast<const bf16x8*>(
          mfrag + (((dt * 2 + kf) << 9) + lane * 8));
  bf16x8 ua[2];
#pragma unroll
  for (int kf = 0; kf < 2; ++kf)
    ua[kf] = *reinterpret_cast<const bf16x8*>(uafr + kf * 512 + lane * 8);
  float4 wf[4];
#pragma unroll
  for (int dt = 0; dt < 4; ++dt)
    wf[dt] = *reinterpret_cast<const float4*>(wvec + dt * 16 + g * 4);
  const float cb = cvec[0];

  asm volatile("s_waitcnt vmcnt(0)" ::: "memory");
  __builtin_amdgcn_sched_barrier(0);

  if (PROBE) {
    // loads-only diagnostic: keep everything live, minimal compute.
    float keep = dot4(Ed[0], Ed[1], 0.f) + dot4(Ed[2], Ed[3], 0.f) + cb;
#pragma unroll
    for (int dt = 0; dt < 4; ++dt) {
      keep = dot4(__builtin_bit_cast(float4, bm[dt][0]), wf[dt], keep);
      keep = dot4(__builtin_bit_cast(float4, bm[dt][1]), wf[dt], keep);
    }
    keep += __builtin_bit_cast(float4, ua[0]).x +
            __builtin_bit_cast(float4, ua[1]).x + L[lane];
    if (lane == 0) dbg[tile] = keep;
    return;
  }

  // --- fragment reads from transposed LDS (conflict-free) ---
  const float4 f0a = *reinterpret_cast<const float4*>(&L[(2 * g) * 64 + c * 4]);
  const float4 f0b = *reinterpret_cast<const float4*>(&L[(2 * g + 1) * 64 + c * 4]);
  const float4 f1a = *reinterpret_cast<const float4*>(&L[(8 + 2 * g) * 64 + c * 4]);
  const float4 f1b = *reinterpret_cast<const float4*>(&L[(9 + 2 * g) * 64 + c * 4]);
  const bf16x8 a0 = cvt8(f0a, f0b);
  const bf16x8 a1 = cvt8(f1a, f1b);

  const f32x4 zero = {0.f, 0.f, 0.f, 0.f};
  f32x4 acc[4];
#pragma unroll
  for (int dt = 0; dt < 4; ++dt) {
    acc[dt] = __builtin_amdgcn_mfma_f32_16x16x32_bf16(bm[dt][0], a0, zero, 0, 0, 0);
    acc[dt] = __builtin_amdgcn_mfma_f32_16x16x32_bf16(bm[dt][1], a1, acc[dt], 0, 0, 0);
  }
  f32x4 accu = __builtin_amdgcn_mfma_f32_16x16x32_bf16(ua[0], a0, zero, 0, 0, 0);
  accu = __builtin_amdgcn_mfma_f32_16x16x32_bf16(ua[1], a1, accu, 0, 0, 0);

  // epilogue: s = e.(H + w) over this lane's 16 d's (+ u.f once, on g==0)
  float s = 0.f;
#pragma unroll
  for (int dt = 0; dt < 4; ++dt) {
    float4 h;
    h.x = acc[dt][0] + wf[dt].x; h.y = acc[dt][1] + wf[dt].y;
    h.z = acc[dt][2] + wf[dt].z; h.w = acc[dt][3] + wf[dt].w;
    s = dot4(Ed[dt], h, s);
  }
  if (g == 0) s += accu[0];
  s += __shfl_xor(s, 16, 64);
  s += __shfl_xor(s, 32, 64);
  if (lane < 16)
    score[rbase + lane] = (s + cb) * 0.125f;
}

// ---------------------------------------------------------------------------
// K3a: per-(64-t-chunk) online (m,s) for ALL b. lane = b -> coalesced reads.
__global__ __launch_bounds__(256) void k3a_partial(
    const float* __restrict__ sc, float* __restrict__ pm,
    float* __restrict__ ps) {
  __shared__ float sm[4][64], ss[4][64];
  const int tid = threadIdx.x;
  const int b = tid & 63;
  const int tq = tid >> 6;
  const int t0 = blockIdx.x * 64;
  float m = -1e30f, s = 0.f;
#pragma unroll
  for (int k = 0; k < 16; ++k) {
    const float v = sc[(size_t)(t0 + k * 4 + tq) * 64 + b];
    const float mn = fmaxf(m, v);
    s = s * __expf(m - mn) + __expf(v - mn);
    m = mn;
  }
  sm[tq][b] = m; ss[tq][b] = s;
  __syncthreads();
  if (tid < 64) {
    float M = sm[0][b], S = ss[0][b];
#pragma unroll
    for (int w = 1; w < 4; ++w) {
      const float m2 = sm[w][b], s2 = ss[w][b];
      const float Mn = fmaxf(M, m2);
      S = S * __expf(M - Mn) + s2 * __expf(m2 - Mn);
      M = Mn;
    }
    pm[blockIdx.x * 64 + b] = M;
    ps[blockIdx.x * 64 + b] = S;
  }
}

// K3b: combine 64 chunk-partials per b. One block.
__global__ __launch_bounds__(64) void k3b_combine(
    const float* __restrict__ pm, const float* __restrict__ ps,
    float* __restrict__ mx, float* __restrict__ inv) {
  const int b = threadIdx.x;
  float M = pm[b], S = ps[b];
#pragma unroll
  for (int ck = 1; ck < 64; ++ck) {
    const float m2 = pm[ck * 64 + b], s2 = ps[ck * 64 + b];
    const float Mn = fmaxf(M, m2);
    S = S * __expf(M - Mn) + s2 * __expf(m2 - Mn);
    M = Mn;
  }
  mx[b] = M;
  inv[b] = 1.0f / S;
}

// ---------------------------------------------------------------------------
// K4: out = eeg + attn*(Wv f + bv). Same staging; stores/E in C-layout.
__global__ __launch_bounds__(256, 2) void k4_output_mfma(
    const float* __restrict__ eeg, const float* __restrict__ fnirs,
    const unsigned short* __restrict__ vfrag, const float* __restrict__ bv,
    const float* __restrict__ score, const float* __restrict__ mx,
    const float* __restrict__ inv, float* __restrict__ out) {
  __shared__ float fstage[4][1024];
  const int tid = threadIdx.x;
  const int lane = tid & 63;
  const int wv = tid >> 6;
  const int tile = blockIdx.x * 4 + wv;
  const int c = lane & 15;
  const int g = lane >> 4;
  const int rbase = tile * 16;
  float* L = fstage[wv];

#pragma unroll
  for (int q = 0; q < 4; ++q) {
    const float* src =
        fnirs + (size_t)(rbase + (lane & 15)) * 64 + (q * 4 + (lane >> 4)) * 4;
    gll16(src, &L[q * 256]);
  }
  float4 Ed[4];
#pragma unroll
  for (int dt = 0; dt < 4; ++dt)
    Ed[dt] = *reinterpret_cast<const float4*>(
        eeg + (size_t)(rbase + c) * 64 + dt * 16 + g * 4);
  bf16x8 bm[4][2];
#pragma unroll
  for (int dt = 0; dt < 4; ++dt)
#pragma unroll
    for (int kf = 0; kf < 2; ++kf)
      bm[dt][kf] = *reinterpret_cast<const bf16x8*>(
          vfrag + (((dt * 2 + kf) << 9) + lane * 8));
  float4 bvf[4];
#pragma unroll
  for (int dt = 0; dt < 4; ++dt)
    bvf[dt] = *reinterpret_cast<const float4*>(bv + dt * 16 + g * 4);
  const float scr = score[rbase + c];
  const int b = (rbase + c) & 63;
  const float mxv = mx[b];
  const float invv = inv[b];

  asm volatile("s_waitcnt vmcnt(0)" ::: "memory");
  __builtin_amdgcn_sched_barrier(0);

  const float4 f0a = *reinterpret_cast<const float4*>(&L[(2 * g) * 64 + c * 4]);
  const float4 f0b = *reinterpret_cast<const float4*>(&L[(2 * g + 1) * 64 + c * 4]);
  const float4 f1a = *reinterpret_cast<const float4*>(&L[(8 + 2 * g) * 64 + c * 4]);
  const float4 f1b = *reinterpret_cast<const float4*>(&L[(9 + 2 * g) * 64 + c * 4]);
  const bf16x8 a0 = cvt8(f0a, f0b);
  const bf16x8 a1 = cvt8(f1a, f1b);

  const f32x4 zero = {0.f, 0.f, 0.f, 0.f};
  f32x4 acc[4];
#pragma unroll
  for (int dt = 0; dt < 4; ++dt) {
    acc[dt] = __builtin_amdgcn_mfma_f32_16x16x32_bf16(bm[dt][0], a0, zero, 0, 0, 0);
    acc[dt] = __builtin_amdgcn_mfma_f32_16x16x32_bf16(bm[dt][1], a1, acc[dt], 0, 0, 0);
  }

  const float aC = __expf(scr - mxv) * invv;
  float* ob = out + (size_t)(rbase + c) * 64;
#pragma unroll
  for (int dt = 0; dt < 4; ++dt) {
    float4 o;
    o.x = fmaf(aC, acc[dt][0] + bvf[dt].x, Ed[dt].x);
    o.y = fmaf(aC, acc[dt][1] + bvf[dt].y, Ed[dt].y);
    o.z = fmaf(aC, acc[dt][2] + bvf[dt].z, Ed[dt].z);
    o.w = fmaf(aC, acc[dt][3] + bvf[dt].w, Ed[dt].w);
    *reinterpret_cast<float4*>(ob + dt * 16 + g * 4) = o;
  }
}

// ---------------------------------------------------------------------------
extern "C" void kernel_launch(void* const* d_in, const int* in_sizes, int n_in,
                              void* d_out, int out_size, void* d_ws, size_t ws_size,
                              hipStream_t stream) {
  const float* eeg   = (const float*)d_in[0];
  const float* fnirs = (const float*)d_in[1];
  const float* Wq    = (const float*)d_in[2];
  const float* bq    = (const float*)d_in[3];
  const float* Wk    = (const float*)d_in[4];
  const float* bk    = (const float*)d_in[5];
  const float* Wv    = (const float*)d_in[6];
  const float* bv    = (const float*)d_in[7];
  float* out = (float*)d_out;
  float* ws  = (float*)d_ws;

  k1_precompute<<<65, 64, 0, stream>>>(Wq, bq, Wk, bk, Wv, ws);
  // diagnostic probe: loads-only k2 (writes scratch; bounds the memory floor)
  k2_score_mfma<1><<<NTILES / 4, 256, 0, stream>>>(
      eeg, fnirs, (const unsigned short*)(ws + WS_MFRAG),
      (const unsigned short*)(ws + WS_UAF), ws + WS_W, ws + WS_C,
      ws + WS_SCORE, ws + WS_DBG);
  k2_score_mfma<0><<<NTILES / 4, 256, 0, stream>>>(
      eeg, fnirs, (const unsigned short*)(ws + WS_MFRAG),
      (const unsigned short*)(ws + WS_UAF), ws + WS_W, ws + WS_C,
      ws + WS_SCORE, ws + WS_DBG);
  k3a_partial<<<64, 256, 0, stream>>>(ws + WS_SCORE, ws + WS_PM, ws + WS_PS);
  k3b_combine<<<1, 64, 0, stream>>>(ws + WS_PM, ws + WS_PS,
                                    ws + WS_MX, ws + WS_INV);
  k4_output_mfma<<<NTILES / 4, 256, 0, stream>>>(
      eeg, fnirs, (const unsigned short*)(ws + WS_VFRAG), bv,
      ws + WS_SCORE, ws + WS_MX, ws + WS_INV, out);
}

// Round 10
// 70.902 us; speedup vs baseline: 1.2668x; 1.2668x over previous
//
#include <hip/hip_runtime.h>
#include <hip/hip_bf16.h>
#include <math.h>

// Problem constants: T=4096, B=64, D=64, SCALE = 1/8.
#define T_DIM 4096
#define B_DIM 64
#define NROWS (T_DIM * B_DIM)   // 262144 rows (r = t*64+b), 64 floats each
#define NTILES (NROWS / 16)     // 16384 16-row MFMA tiles; 4 per wave

// Workspace layout (float offsets)
#define WS_MFRAG 0        // 4096 u16 (2048 f): M fragment-linear bf16
#define WS_VFRAG 2048     // 4096 u16: Wv fragment-linear bf16
#define WS_U     4096     // 64 f32: u[k] = sum_o bq[o]*Wk[o,k]
#define WS_W     4160     // 64 f32: w[d] = sum_o Wq[o,d]*bk[o]
#define WS_C     4224     // 1 f32:  c = bq.bk
#define WS_MX    4240     // 64 f32 per-b max
#define WS_INV   4304     // 64 f32 per-b 1/sum
#define WS_PM    4368     // 64x64 f32 partial max
#define WS_PS    8464     // 64x64 f32 partial sum
#define WS_SCORE 16384    // [NROWS] scores, natural r order

typedef __attribute__((ext_vector_type(4))) float f32x4;
typedef __attribute__((ext_vector_type(8))) short bf16x8;

static __device__ inline short f2bf(float x) {
  __hip_bfloat16 h = __float2bfloat16(x);
  return *reinterpret_cast<short*>(&h);
}

static __device__ inline bf16x8 cvt8(const float4 a, const float4 b) {
  bf16x8 r;
  r[0] = f2bf(a.x); r[1] = f2bf(a.y); r[2] = f2bf(a.z); r[3] = f2bf(a.w);
  r[4] = f2bf(b.x); r[5] = f2bf(b.y); r[6] = f2bf(b.z); r[7] = f2bf(b.w);
  return r;
}

static __device__ inline float dot4(const float4 a, const float4 b, float acc) {
  acc = fmaf(a.x, b.x, acc); acc = fmaf(a.y, b.y, acc);
  acc = fmaf(a.z, b.z, acc); acc = fmaf(a.w, b.w, acc);
  return acc;
}

// Fragment-linear index (u16 units) for weight element W[d][k].
static __device__ __host__ inline int frag_idx(int d, int k) {
  return ((d >> 4) * 2 + (k >> 5)) * 512 +
         ((((k >> 3) & 3) * 16 + (d & 15)) * 8) + (k & 7);
}

// 16B/lane global->LDS staging (no VGPR dest: cannot be serialized by RA).
static __device__ inline void gll16(const float* src, float* ldsbase) {
  __builtin_amdgcn_global_load_lds(
      (const __attribute__((address_space(1))) unsigned int*)src,
      (__attribute__((address_space(3))) unsigned int*)ldsbase, 16, 0, 0);
}

// ---------------------------------------------------------------------------
// K1: bilinear constants; M and Wv bf16 fragment-linear; u,w,c f32.
__global__ __launch_bounds__(64) void k1_precompute(
    const float* __restrict__ Wq, const float* __restrict__ bq,
    const float* __restrict__ Wk, const float* __restrict__ bk,
    const float* __restrict__ Wv, float* __restrict__ ws) {
  const int tid = threadIdx.x;
  const int blk = blockIdx.x;
  unsigned short* __restrict__ mfrag = (unsigned short*)(ws + WS_MFRAG);
  unsigned short* __restrict__ vfrag = (unsigned short*)(ws + WS_VFRAG);
  if (blk < 64) {
    const int d = blk;
    float acc = 0.f;
#pragma unroll
    for (int o = 0; o < 64; ++o)
      acc = fmaf(Wq[o * 64 + d], Wk[o * 64 + tid], acc);
    const int idx = frag_idx(d, tid);
    mfrag[idx] = (unsigned short)f2bf(acc);
    vfrag[idx] = (unsigned short)f2bf(Wv[d * 64 + tid]);
  } else {
    float uacc = 0.f, wacc = 0.f, cacc = 0.f;
#pragma unroll
    for (int o = 0; o < 64; ++o) {
      uacc = fmaf(bq[o], Wk[o * 64 + tid], uacc);
      wacc = fmaf(Wq[o * 64 + tid], bk[o], wacc);
      cacc = fmaf(bq[o], bk[o], cacc);
    }
    ws[WS_U + tid] = uacc;
    ws[WS_W + tid] = wacc;
    if (tid == 0) ws[WS_C] = cacc;
  }
}

// ---------------------------------------------------------------------------
// K2: score[r] = 0.125*(e^T M f + w.e + u.f + c).
// Weights: LDS once per block -> registers once per wave. Per tile: exactly
// 8 global_load_lds ops (F,E transposed chunk-major), counted-vmcnt 2-deep
// pipeline, 4 tiles per wave fully unrolled.

#define K2_STAGE(b_, t_)                                                      \
  {                                                                           \
    const size_t rb_ = (size_t)(t_) * 16;                                     \
    float* Lb_ = &stg[wv][b_][0];                                             \
    _Pragma("unroll") for (int q = 0; q < 4; ++q)                             \
        gll16(fnirs + (rb_ + (lane & 15)) * 64 + (q * 4 + (lane >> 4)) * 4,   \
              Lb_ + q * 256);                                                 \
    _Pragma("unroll") for (int q = 0; q < 4; ++q)                             \
        gll16(eeg + (rb_ + (lane & 15)) * 64 + (q * 4 + (lane >> 4)) * 4,     \
              Lb_ + 1024 + q * 256);                                          \
  }

#define K2_COMP(b_, t_)                                                       \
  {                                                                           \
    const float* LF_ = &stg[wv][b_][0];                                       \
    const float* LE_ = &stg[wv][b_][1024];                                    \
    const float4 f0a_ = *reinterpret_cast<const float4*>(LF_ + (2 * g) * 64 + c * 4); \
    const float4 f0b_ = *reinterpret_cast<const float4*>(LF_ + (2 * g + 1) * 64 + c * 4); \
    const float4 f1a_ = *reinterpret_cast<const float4*>(LF_ + (8 + 2 * g) * 64 + c * 4); \
    const float4 f1b_ = *reinterpret_cast<const float4*>(LF_ + (9 + 2 * g) * 64 + c * 4); \
    float s_ = dot4(f0a_, u0a, dot4(f0b_, u0b, dot4(f1a_, u1a, dot4(f1b_, u1b, 0.f)))); \
    const bf16x8 a0_ = cvt8(f0a_, f0b_);                                      \
    const bf16x8 a1_ = cvt8(f1a_, f1b_);                                      \
    f32x4 acc_[4];                                                            \
    _Pragma("unroll") for (int dt = 0; dt < 4; ++dt) {                        \
      acc_[dt] = __builtin_amdgcn_mfma_f32_16x16x32_bf16(bm[dt][0], a0_, zero, 0, 0, 0); \
      acc_[dt] = __builtin_amdgcn_mfma_f32_16x16x32_bf16(bm[dt][1], a1_, acc_[dt], 0, 0, 0); \
    }                                                                         \
    _Pragma("unroll") for (int dt = 0; dt < 4; ++dt) {                        \
      const float4 Ed_ = *reinterpret_cast<const float4*>(LE_ + (dt * 4 + g) * 64 + c * 4); \
      float4 h_;                                                              \
      h_.x = acc_[dt][0] + wfr[dt].x; h_.y = acc_[dt][1] + wfr[dt].y;         \
      h_.z = acc_[dt][2] + wfr[dt].z; h_.w = acc_[dt][3] + wfr[dt].w;         \
      s_ = dot4(Ed_, h_, s_);                                                 \
    }                                                                         \
    s_ += __shfl_xor(s_, 16, 64);                                             \
    s_ += __shfl_xor(s_, 32, 64);                                             \
    if (lane < 16) score[(t_) * 16 + lane] = (s_ + cb) * 0.125f;              \
  }

__global__ __launch_bounds__(256, 2) void k2_score_mfma(
    const float* __restrict__ eeg, const float* __restrict__ fnirs,
    const float* __restrict__ wsf, float* __restrict__ score) {
  __shared__ float stg[4][2][2048];       // [wave][buf][F|E] = 64 KB
  __shared__ unsigned short mw[4096];     // M fragment-linear, 8 KB
  __shared__ float wl[64];                // w vector

  const int tid = threadIdx.x;
  const int lane = tid & 63;
  const int wv = tid >> 6;
  const int c = lane & 15;
  const int g = lane >> 4;

  // prologue: weights -> LDS (once per block)
  {
    const float4* msrc = reinterpret_cast<const float4*>(wsf + WS_MFRAG);
    float4* mdst = reinterpret_cast<float4*>(mw);
    mdst[tid] = msrc[tid];
    mdst[tid + 256] = msrc[tid + 256];
    if (tid < 64) wl[tid] = wsf[WS_W + tid];
  }
  __syncthreads();

  // per-wave registers (once)
  bf16x8 bm[4][2];
#pragma unroll
  for (int dt = 0; dt < 4; ++dt)
#pragma unroll
    for (int kf = 0; kf < 2; ++kf)
      bm[dt][kf] = *reinterpret_cast<const bf16x8*>(
          mw + (((dt * 2 + kf) << 9) + lane * 8));
  float4 wfr[4];
#pragma unroll
  for (int dt = 0; dt < 4; ++dt)
    wfr[dt] = *reinterpret_cast<const float4*>(&wl[dt * 16 + g * 4]);
  const float4 u0a = *reinterpret_cast<const float4*>(wsf + WS_U + g * 8);
  const float4 u0b = *reinterpret_cast<const float4*>(wsf + WS_U + g * 8 + 4);
  const float4 u1a = *reinterpret_cast<const float4*>(wsf + WS_U + 32 + g * 8);
  const float4 u1b = *reinterpret_cast<const float4*>(wsf + WS_U + 36 + g * 8);
  const float cb = wsf[WS_C];
  const f32x4 zero = {0.f, 0.f, 0.f, 0.f};

  const int t0 = (blockIdx.x * 4 + wv) * 4;

  K2_STAGE(0, t0);
  K2_STAGE(1, t0 + 1);
  asm volatile("s_waitcnt vmcnt(8)" ::: "memory");
  __builtin_amdgcn_sched_barrier(0);
  K2_COMP(0, t0);
  K2_STAGE(0, t0 + 2);
  asm volatile("s_waitcnt vmcnt(8)" ::: "memory");
  __builtin_amdgcn_sched_barrier(0);
  K2_COMP(1, t0 + 1);
  K2_STAGE(1, t0 + 3);
  asm volatile("s_waitcnt vmcnt(8)" ::: "memory");
  __builtin_amdgcn_sched_barrier(0);
  K2_COMP(0, t0 + 2);
  asm volatile("s_waitcnt vmcnt(0)" ::: "memory");
  __builtin_amdgcn_sched_barrier(0);
  K2_COMP(1, t0 + 3);
}

// ---------------------------------------------------------------------------
// K3a: per-(64-t-chunk) online (m,s) for ALL b. lane = b -> coalesced reads.
__global__ __launch_bounds__(256) void k3a_partial(
    const float* __restrict__ sc, float* __restrict__ pm,
    float* __restrict__ ps) {
  __shared__ float sm[4][64], ss[4][64];
  const int tid = threadIdx.x;
  const int b = tid & 63;
  const int tq = tid >> 6;
  const int t0 = blockIdx.x * 64;
  float m = -1e30f, s = 0.f;
#pragma unroll
  for (int k = 0; k < 16; ++k) {
    const float v = sc[(size_t)(t0 + k * 4 + tq) * 64 + b];
    const float mn = fmaxf(m, v);
    s = s * __expf(m - mn) + __expf(v - mn);
    m = mn;
  }
  sm[tq][b] = m; ss[tq][b] = s;
  __syncthreads();
  if (tid < 64) {
    float M = sm[0][b], S = ss[0][b];
#pragma unroll
    for (int w = 1; w < 4; ++w) {
      const float m2 = sm[w][b], s2 = ss[w][b];
      const float Mn = fmaxf(M, m2);
      S = S * __expf(M - Mn) + s2 * __expf(m2 - Mn);
      M = Mn;
    }
    pm[blockIdx.x * 64 + b] = M;
    ps[blockIdx.x * 64 + b] = S;
  }
}

// K3b: combine 64 chunk-partials per b. One block.
__global__ __launch_bounds__(64) void k3b_combine(
    const float* __restrict__ pm, const float* __restrict__ ps,
    float* __restrict__ mx, float* __restrict__ inv) {
  const int b = threadIdx.x;
  float M = pm[b], S = ps[b];
#pragma unroll
  for (int ck = 1; ck < 64; ++ck) {
    const float m2 = pm[ck * 64 + b], s2 = ps[ck * 64 + b];
    const float Mn = fmaxf(M, m2);
    S = S * __expf(M - Mn) + s2 * __expf(m2 - Mn);
    M = Mn;
  }
  mx[b] = M;
  inv[b] = 1.0f / S;
}

// ---------------------------------------------------------------------------
// K4: out = eeg + attn*(Wv f + bv). Same pipeline; +1 score load per stage.

#define K4_STAGE(b_, t_, scv_)                                                \
  {                                                                           \
    const size_t rb_ = (size_t)(t_) * 16;                                     \
    float* Lb_ = &stg[wv][b_][0];                                             \
    _Pragma("unroll") for (int q = 0; q < 4; ++q)                             \
        gll16(fnirs + (rb_ + (lane & 15)) * 64 + (q * 4 + (lane >> 4)) * 4,   \
              Lb_ + q * 256);                                                 \
    _Pragma("unroll") for (int q = 0; q < 4; ++q)                             \
        gll16(eeg + (rb_ + (lane & 15)) * 64 + (q * 4 + (lane >> 4)) * 4,     \
              Lb_ + 1024 + q * 256);                                          \
    scv_ = score[(t_) * 16 + c];                                              \
  }

#define K4_COMP(b_, t_, scv_)                                                 \
  {                                                                           \
    const float* LF_ = &stg[wv][b_][0];                                       \
    const float* LE_ = &stg[wv][b_][1024];                                    \
    const float4 f0a_ = *reinterpret_cast<const float4*>(LF_ + (2 * g) * 64 + c * 4); \
    const float4 f0b_ = *reinterpret_cast<const float4*>(LF_ + (2 * g + 1) * 64 + c * 4); \
    const float4 f1a_ = *reinterpret_cast<const float4*>(LF_ + (8 + 2 * g) * 64 + c * 4); \
    const float4 f1b_ = *reinterpret_cast<const float4*>(LF_ + (9 + 2 * g) * 64 + c * 4); \
    const bf16x8 a0_ = cvt8(f0a_, f0b_);                                      \
    const bf16x8 a1_ = cvt8(f1a_, f1b_);                                      \
    f32x4 acc_[4];                                                            \
    _Pragma("unroll") for (int dt = 0; dt < 4; ++dt) {                        \
      acc_[dt] = __builtin_amdgcn_mfma_f32_16x16x32_bf16(bm[dt][0], a0_, zero, 0, 0, 0); \
      acc_[dt] = __builtin_amdgcn_mfma_f32_16x16x32_bf16(bm[dt][1], a1_, acc_[dt], 0, 0, 0); \
    }                                                                         \
    const int bl_ = (((t_) * 16) & 63) + c;                                   \
    const float aC_ = __expf((scv_) - mxl[bl_]) * invl[bl_];                  \
    float* ob_ = out + ((size_t)(t_) * 16 + c) * 64;                          \
    _Pragma("unroll") for (int dt = 0; dt < 4; ++dt) {                        \
      const float4 Ed_ = *reinterpret_cast<const float4*>(LE_ + (dt * 4 + g) * 64 + c * 4); \
      float4 o_;                                                              \
      o_.x = fmaf(aC_, acc_[dt][0] + bvf[dt].x, Ed_.x);                       \
      o_.y = fmaf(aC_, acc_[dt][1] + bvf[dt].y, Ed_.y);                       \
      o_.z = fmaf(aC_, acc_[dt][2] + bvf[dt].z, Ed_.z);                       \
      o_.w = fmaf(aC_, acc_[dt][3] + bvf[dt].w, Ed_.w);                       \
      *reinterpret_cast<float4*>(ob_ + dt * 16 + g * 4) = o_;                 \
    }                                                                         \
  }

__global__ __launch_bounds__(256, 2) void k4_output_mfma(
    const float* __restrict__ eeg, const float* __restrict__ fnirs,
    const float* __restrict__ wsf, const float* __restrict__ bv,
    const float* __restrict__ score, float* __restrict__ out) {
  __shared__ float stg[4][2][2048];       // 64 KB
  __shared__ unsigned short vw[4096];     // Wv fragment-linear, 8 KB
  __shared__ float bvl[64], mxl[64], invl[64];

  const int tid = threadIdx.x;
  const int lane = tid & 63;
  const int wv = tid >> 6;
  const int c = lane & 15;
  const int g = lane >> 4;

  {
    const float4* vsrc = reinterpret_cast<const float4*>(wsf + WS_VFRAG);
    float4* vdst = reinterpret_cast<float4*>(vw);
    vdst[tid] = vsrc[tid];
    vdst[tid + 256] = vsrc[tid + 256];
    if (tid < 64) {
      bvl[tid] = bv[tid];
      mxl[tid] = wsf[WS_MX + tid];
      invl[tid] = wsf[WS_INV + tid];
    }
  }
  __syncthreads();

  bf16x8 bm[4][2];
#pragma unroll
  for (int dt = 0; dt < 4; ++dt)
#pragma unroll
    for (int kf = 0; kf < 2; ++kf)
      bm[dt][kf] = *reinterpret_cast<const bf16x8*>(
          vw + (((dt * 2 + kf) << 9) + lane * 8));
  float4 bvf[4];
#pragma unroll
  for (int dt = 0; dt < 4; ++dt)
    bvf[dt] = *reinterpret_cast<const float4*>(&bvl[dt * 16 + g * 4]);
  const f32x4 zero = {0.f, 0.f, 0.f, 0.f};

  const int t0 = (blockIdx.x * 4 + wv) * 4;
  float scA, scB;

  K4_STAGE(0, t0, scA);
  K4_STAGE(1, t0 + 1, scB);
  asm volatile("s_waitcnt vmcnt(9)" ::: "memory");
  __builtin_amdgcn_sched_barrier(0);
  K4_COMP(0, t0, scA);
  K4_STAGE(0, t0 + 2, scA);
  asm volatile("s_waitcnt vmcnt(9)" ::: "memory");
  __builtin_amdgcn_sched_barrier(0);
  K4_COMP(1, t0 + 1, scB);
  K4_STAGE(1, t0 + 3, scB);
  asm volatile("s_waitcnt vmcnt(9)" ::: "memory");
  __builtin_amdgcn_sched_barrier(0);
  K4_COMP(0, t0 + 2, scA);
  asm volatile("s_waitcnt vmcnt(0)" ::: "memory");
  __builtin_amdgcn_sched_barrier(0);
  K4_COMP(1, t0 + 3, scB);
}

// ---------------------------------------------------------------------------
extern "C" void kernel_launch(void* const* d_in, const int* in_sizes, int n_in,
                              void* d_out, int out_size, void* d_ws, size_t ws_size,
                              hipStream_t stream) {
  const float* eeg   = (const float*)d_in[0];
  const float* fnirs = (const float*)d_in[1];
  const float* Wq    = (const float*)d_in[2];
  const float* bq    = (const float*)d_in[3];
  const float* Wk    = (const float*)d_in[4];
  const float* bk    = (const float*)d_in[5];
  const float* Wv    = (const float*)d_in[6];
  const float* bv    = (const float*)d_in[7];
  float* out = (float*)d_out;
  float* ws  = (float*)d_ws;

  k1_precompute<<<65, 64, 0, stream>>>(Wq, bq, Wk, bk, Wv, ws);
  k2_score_mfma<<<NTILES / 16, 256, 0, stream>>>(eeg, fnirs, ws, ws + WS_SCORE);
  k3a_partial<<<64, 256, 0, stream>>>(ws + WS_SCORE, ws + WS_PM, ws + WS_PS);
  k3b_combine<<<1, 64, 0, stream>>>(ws + WS_PM, ws + WS_PS,
                                    ws + WS_MX, ws + WS_INV);
  k4_output_mfma<<<NTILES / 16, 256, 0, stream>>>(eeg, fnirs, ws, bv,
                                                  ws + WS_SCORE, out);
}